// Round 8
// baseline (177.238 us; speedup 1.0000x reference)
//
#include <hip/hip_runtime.h>
#include <hip/hip_bf16.h>

typedef short short8 __attribute__((ext_vector_type(8)));
typedef short short4v __attribute__((ext_vector_type(4)));
typedef float f32x4 __attribute__((ext_vector_type(4)));

constexpr int BB = 8192;   // batch
constexpr int LL = 50;     // seq len
constexpr int DE = 128;    // emb dim
constexpr int DD = 392;    // total input dim
constexpr int HH1 = 256;
constexpr int HH2 = 128;

__device__ __forceinline__ short f2b(float x) {
    __hip_bfloat16 h = __float2bfloat16(x);   // RNE
    return __builtin_bit_cast(short, h);
}
__device__ __forceinline__ float b2f(short v) {
    unsigned u = ((unsigned)(unsigned short)v) << 16;
    return __builtin_bit_cast(float, u);
}

// ---------------------------------------------------------------------------
// prep A (one launch, 68 blocks):
//  b<32 : WqpT[h][d] = bf16(W1q + W1(q-k))  transposed [64][128]
//  b<64 : WkpFf interleaved frag table (f32): [kt][nt][lane][ wk(8) | wp(8) ]
//  b<68 : hw2[e][k][t] = exp_w2[e][k][:] . head_w[t][:]; hc[e][t] from bias
// ---------------------------------------------------------------------------
__global__ __launch_bounds__(256) void prep_small(
    const float* __restrict__ w1,
    const float* __restrict__ w2, const float* __restrict__ b2,
    const float* __restrict__ head_w,
    short* __restrict__ WqpT, float* __restrict__ WkpFf,
    float* __restrict__ hw2, float* __restrict__ hc)
{
    __shared__ float hw[256];
    const int b = blockIdx.x, t = threadIdx.x;
    if (b < 32) {
        int o = b * 256 + t;                // h*128 + d
        int h = o >> 7, d = o & 127;
        WqpT[o] = f2b(w1[d * 64 + h] + w1[16384 + d * 64 + h]);
    } else if (b < 64) {
        int o = (b - 32) * 256 + t;         // [kt][nt][lane][e] index, 8192
        int e = o & 7, lane = (o >> 3) & 63, nt = (o >> 9) & 3, kt = o >> 11;
        int k = (kt << 5) + ((lane >> 4) << 3) + e;
        int h = (nt << 4) + (lane & 15);
        int base = (o >> 3) << 4;
        WkpFf[base + e]     = w1[(128 + k) * 64 + h] - w1[(256 + k) * 64 + h];
        WkpFf[base + 8 + e] = w1[(384 + k) * 64 + h];
    } else {
        const int e = b - 64;
        hw[t] = head_w[t];
        __syncthreads();
        const float* row = &w2[((long)e * HH1 + t) * HH2];
        float s0 = 0.f, s1 = 0.f;
        #pragma unroll 8
        for (int o = 0; o < 128; o += 4) {
            float4 v = *reinterpret_cast<const float4*>(&row[o]);
            s0 += v.x * hw[o] + v.y * hw[o + 1] + v.z * hw[o + 2] + v.w * hw[o + 3];
            s1 += v.x * hw[128 + o] + v.y * hw[129 + o] + v.z * hw[130 + o] + v.w * hw[131 + o];
        }
        hw2[(((e << 8) + t) << 1) + 0] = s0;
        hw2[(((e << 8) + t) << 1) + 1] = s1;
        if (t < 2) {
            float s = 0.f;
            for (int o = 0; o < 128; ++o) s += b2[e * 128 + o] * hw[t * 128 + o];
            hc[e * 2 + t] = s;
        }
    }
}

// ---------------------------------------------------------------------------
// prep B (one launch): WTc (cross W^T), WT1 (exp_w1^T), embB (bf16 movie
// table), qb (bf16 gathered q rows for the qconst GEMM)
// ---------------------------------------------------------------------------
constexpr int S0 = 3 * 392 * 392;        // 460992
constexpr int S1 = 4 * 392 * 256;        // 401408
constexpr int S2 = (50001 * 128) / 4;    // 1600032 (4 elems each)
constexpr int S3 = (BB * 128) / 4;       // 262144  (4 elems each)

__global__ __launch_bounds__(256) void prep_trans(
    const float* __restrict__ cross_W, const float* __restrict__ exp_w1,
    const float* __restrict__ emb_movie, const int* __restrict__ movieId,
    short* __restrict__ WTc, short* __restrict__ WT1, short* __restrict__ embB,
    short* __restrict__ qb)
{
    int idx = blockIdx.x * 256 + threadIdx.x;
    if (idx < S0) {
        int z = idx / (392 * 392), rr = idx - z * 392 * 392;
        int c = rr / 392, r = rr - c * 392;
        WTc[idx] = f2b(cross_W[(long)z * 153664 + r * 392 + c]);
    } else if (idx < S0 + S1) {
        int j = idx - S0;
        int z = j / 100352, rr = j - z * 100352;
        int c = rr / 392, r = rr - c * 392;
        WT1[j] = f2b(exp_w1[(long)z * 100352 + r * 256 + c]);
    } else if (idx < S0 + S1 + S2) {
        long j = (long)(idx - S0 - S1) << 2;
        float4 v = *reinterpret_cast<const float4*>(&emb_movie[j]);
        short4v o;
        o[0] = f2b(v.x); o[1] = f2b(v.y); o[2] = f2b(v.z); o[3] = f2b(v.w);
        *reinterpret_cast<short4v*>(&embB[j]) = o;
    } else if (idx < S0 + S1 + S2 + S3) {
        int j = idx - S0 - S1 - S2;
        int bb = j >> 5, d0 = (j & 31) << 2;
        float4 v = *reinterpret_cast<const float4*>(
            &emb_movie[(long)movieId[bb] * DE + d0]);
        short4v o;
        o[0] = f2b(v.x); o[1] = f2b(v.y); o[2] = f2b(v.z); o[3] = f2b(v.w);
        *reinterpret_cast<short4v*>(&qb[bb * DE + d0]) = o;
    }
}

// ---------------------------------------------------------------------------
// K1: DIN attention (MFMA, q folded into B) + concat + LayerNorm1 -> x0
// qconst precomputed (qcAll); Wk/Wp tables f32; 7-barrier schedule.
// ---------------------------------------------------------------------------
__global__ __launch_bounds__(256, 8) void attn_kernel(
    const int* __restrict__ userId, const int* __restrict__ movieId,
    const int* __restrict__ seq, const float* __restrict__ dense,
    const float* __restrict__ emb_user, const float* __restrict__ emb_movie,
    const short* __restrict__ embB,
    const float* __restrict__ qcAll, const float* __restrict__ WkpFf,
    const float* __restrict__ att_w2, const float* __restrict__ att_b2,
    const float* __restrict__ in_gamma, const float* __restrict__ in_beta,
    float* __restrict__ x0f, short* __restrict__ x0b)
{
    __shared__ short hist[64 * 128];    // swizzled: byte = l*256 + (bytecol ^ ((l&7)<<4))
    __shared__ float qs[128];
    __shared__ int   seq_s[64];
    __shared__ float spS[4][64];        // score partials, later LN partials
    __shared__ float probs[64];
    __shared__ float ibuf[4][128];      // interest partials
    __shared__ float stats[2];

    const int b = blockIdx.x;
    const int t = threadIdx.x;
    const int lane = t & 63;
    const int w = t >> 6;

    if (t < 128) qs[t] = emb_movie[(long)movieId[b] * DE + t];
    if (t < 64)  seq_s[t] = (t < LL) ? seq[b * LL + t] : 0;
    __syncthreads();   // A

    // stage hist bf16 swizzled, branchless (seq_s[l>=LL]=0 -> zero row)
    #pragma unroll
    for (int i = 0; i < 4; ++i) {
        const int idx = t + (i << 8);
        const int l = idx >> 4, c = idx & 15;
        short8 hv = *reinterpret_cast<const short8*>(&embB[(long)seq_s[l] * DE + (c << 3)]);
        const int byte = (l << 8) + ((c << 4) ^ ((l & 7) << 4));
        *reinterpret_cast<short8*>(reinterpret_cast<char*>(hist) + byte) = hv;
    }

    // hoisted independent gathers
    const int col = (w << 4) + (lane & 15);
    float ue = (t < 128) ? emb_user[(long)userId[b] * DE + t] : 0.f;
    float dv = (t >= 128 && t < 136) ? dense[b * 8 + (t - 128)] : 0.f;
    const float qc  = qcAll[((long)b << 6) + col];
    const float w2v = att_w2[col];

    // per-row B fragments: V[k][h] = Wk'[k][h] + q[k]*Wp[k][h]  (f32 tables)
    short8 bfrag[4];
    #pragma unroll
    for (int kt = 0; kt < 4; ++kt) {
        const float* wkp = &WkpFf[((((kt << 2) + w) << 6) | lane) << 4];
        const int kq = (kt << 5) + ((lane >> 4) << 3);
        #pragma unroll
        for (int j = 0; j < 8; ++j)
            bfrag[kt][j] = f2b(fmaf(qs[kq + j], wkp[8 + j], wkp[j]));
    }
    __syncthreads();   // B (hist ready)

    // MFMA per m-tile, qconst added post-MFMA, reduce to score partials
    #pragma unroll
    for (int mt = 0; mt < 4; ++mt) {
        f32x4 acc = {0.f, 0.f, 0.f, 0.f};
        const int row = (mt << 4) + (lane & 15);
        const int rbase = row << 8;
        const int swz = (row & 7) << 4;
        #pragma unroll
        for (int kt = 0; kt < 4; ++kt) {
            const int kbyte = (kt << 6) + ((lane >> 4) << 4);
            short8 a = *reinterpret_cast<const short8*>(
                reinterpret_cast<char*>(hist) + rbase + (kbyte ^ swz));
            acc = __builtin_amdgcn_mfma_f32_16x16x32_bf16(a, bfrag[kt], acc, 0, 0, 0);
        }
        #pragma unroll
        for (int r = 0; r < 4; ++r) {
            float v = fmaxf(acc[r] + qc, 0.f) * w2v;
            v += __shfl_xor(v, 1); v += __shfl_xor(v, 2);
            v += __shfl_xor(v, 4); v += __shfl_xor(v, 8);
            if ((lane & 15) == 0)
                spS[w][(mt << 4) + ((lane >> 4) << 2) + r] = v;
        }
    }
    __syncthreads();   // C

    // masked softmax over l (threads 0..63); probs[l>=LL] = 0
    if (t < 64) {
        float sc = spS[0][t] + spS[1][t] + spS[2][t] + spS[3][t] + att_b2[0];
        float s = (t < LL) ? ((seq_s[t] > 0) ? sc : -1e9f) : -INFINITY;
        float m = s;
        #pragma unroll
        for (int off = 32; off > 0; off >>= 1) m = fmaxf(m, __shfl_xor(m, off));
        float e = (t < LL) ? __expf(s - m) : 0.f;
        float sum = e;
        #pragma unroll
        for (int off = 32; off > 0; off >>= 1) sum += __shfl_xor(sum, off);
        probs[t] = (t < LL) ? (e / sum) : 0.f;
    }
    __syncthreads();   // D

    // interest partials from the LDS bf16 hist
    const int g  = t >> 5;
    const int d0 = (t & 31) << 2;
    float4 ps = make_float4(0.f, 0.f, 0.f, 0.f);
    #pragma unroll
    for (int i = 0; i < 8; ++i) {
        const int l = g + (i << 3);
        const int byte = (l << 8) + ((d0 << 1) ^ ((l & 7) << 4));
        short4v hv = *reinterpret_cast<const short4v*>(
            reinterpret_cast<const char*>(hist) + byte);
        const float p = probs[l];
        ps.x = fmaf(p, b2f(hv[0]), ps.x);
        ps.y = fmaf(p, b2f(hv[1]), ps.y);
        ps.z = fmaf(p, b2f(hv[2]), ps.z);
        ps.w = fmaf(p, b2f(hv[3]), ps.w);
    }
    ps.x += __shfl_xor(ps.x, 32); ps.y += __shfl_xor(ps.y, 32);
    ps.z += __shfl_xor(ps.z, 32); ps.w += __shfl_xor(ps.w, 32);
    if (lane < 32)
        *reinterpret_cast<float4*>(&ibuf[w][lane << 2]) = ps;
    __syncthreads();   // E (ibuf ready; spS reusable)

    // LN inputs directly in registers
    float v0 = (t < 128) ? ue : qs[t - 128];
    float v1 = 0.f;
    if (t < 128)       v1 = ibuf[0][t] + ibuf[1][t] + ibuf[2][t] + ibuf[3][t];
    else if (t < 136)  v1 = dv;

    float s2 = v0 + v1, q2 = v0 * v0 + v1 * v1;
    #pragma unroll
    for (int off = 32; off > 0; off >>= 1) {
        s2 += __shfl_xor(s2, off);
        q2 += __shfl_xor(q2, off);
    }
    if (lane == 0) { spS[0][w] = s2; spS[1][w] = q2; }
    __syncthreads();   // F
    if (t == 0) {
        float S = spS[0][0] + spS[0][1] + spS[0][2] + spS[0][3];
        float Q = spS[1][0] + spS[1][1] + spS[1][2] + spS[1][3];
        float mean = S / (float)DD;
        float var = Q / (float)DD - mean * mean;
        stats[0] = mean;
        stats[1] = rsqrtf(var + 1e-5f);
    }
    __syncthreads();   // G
    const float mean = stats[0], inv = stats[1];
    const long base = (long)b * DD;
    float o0 = (v0 - mean) * inv * in_gamma[t] + in_beta[t];
    x0f[base + t] = o0; x0b[base + t] = f2b(o0);
    if (t < 136) {
        float o1 = (v1 - mean) * inv * in_gamma[256 + t] + in_beta[256 + t];
        x0f[base + 256 + t] = o1; x0b[base + 256 + t] = f2b(o1);
    }
}

// ---------------------------------------------------------------------------
// bf16 MFMA GEMM, 2-deep register prefetch + double-buffered LDS + XCD swizzle.
// out = f(A[M,K](bf16) @ WT[N,K]^T(bf16) + bias)
// MODE 0: +bias ; 1: relu(+bias) ; 2: cross: out = x0*(acc+bias)+xin
// 1-D grid, id m-major: id = mb*(NXB*NZB) + z*NXB + xb. grid%8 must be 0.
// ---------------------------------------------------------------------------
template<int MODE, int WF32, int WB16, int NXB, int NZB>
__global__ __launch_bounds__(256) void bgemm(
    const short* __restrict__ A, const short* __restrict__ WT,
    const float* __restrict__ bias,
    float* __restrict__ outF, short* __restrict__ outB,
    const float* __restrict__ x0, const float* __restrict__ xin,
    int M, int N, int K, long aZ, long wZ, long bZ, long oZ)
{
    __shared__ short As[2][64 * 64];   // swizzled: byte = r*128 + ((k*2)^((r&7)<<4))
    __shared__ short Bs[2][64 * 64];

    int id = blockIdx.x;
    const int qq = (int)gridDim.x >> 3;
    id = (id & 7) * qq + (id >> 3);
    const int mb  = id / (NXB * NZB);
    const int rem = id - mb * (NXB * NZB);
    const int z   = rem / NXB;
    const int xb  = rem - z * NXB;

    A += (long)z * aZ; WT += (long)z * wZ; bias += (long)z * bZ;
    const long oz = (long)z * oZ;

    const int t = threadIdx.x, w = t >> 6, lane = t & 63;
    const int m0 = mb * 64, n0 = xb * 64;
    const int sm = t >> 3, sk8 = (t & 7) << 3;

    f32x4 acc[4];
    #pragma unroll
    for (int i = 0; i < 4; ++i) {
        #pragma unroll
        for (int r = 0; r < 4; ++r) acc[i][r] = 0.f;
    }

    const int nsteps = (K + 63) >> 6;
    short8 avA[2], bvA[2], avB[2], bvB[2];

    auto loadA = [&](int k0) {
        #pragma unroll
        for (int i = 0; i < 2; ++i) {
            const int r = sm + (i << 5);
            short8 zv = {0, 0, 0, 0, 0, 0, 0, 0};
            avA[i] = zv; bvA[i] = zv;
            if (k0 + sk8 < K) {
                avA[i] = *reinterpret_cast<const short8*>(&A[(long)(m0 + r) * K + k0 + sk8]);
                if (n0 + r < N)
                    bvA[i] = *reinterpret_cast<const short8*>(&WT[(long)(n0 + r) * K + k0 + sk8]);
            }
        }
    };
    auto loadB = [&](int k0) {
        #pragma unroll
        for (int i = 0; i < 2; ++i) {
            const int r = sm + (i << 5);
            short8 zv = {0, 0, 0, 0, 0, 0, 0, 0};
            avB[i] = zv; bvB[i] = zv;
            if (k0 + sk8 < K) {
                avB[i] = *reinterpret_cast<const short8*>(&A[(long)(m0 + r) * K + k0 + sk8]);
                if (n0 + r < N)
                    bvB[i] = *reinterpret_cast<const short8*>(&WT[(long)(n0 + r) * K + k0 + sk8]);
            }
        }
    };
    auto wrA = [&](int buf) {
        #pragma unroll
        for (int i = 0; i < 2; ++i) {
            const int r = sm + (i << 5);
            const int byte = (r << 7) + ((sk8 << 1) ^ ((r & 7) << 4));
            *reinterpret_cast<short8*>(reinterpret_cast<char*>(&As[buf][0]) + byte) = avA[i];
            *reinterpret_cast<short8*>(reinterpret_cast<char*>(&Bs[buf][0]) + byte) = bvA[i];
        }
    };
    auto wrB = [&](int buf) {
        #pragma unroll
        for (int i = 0; i < 2; ++i) {
            const int r = sm + (i << 5);
            const int byte = (r << 7) + ((sk8 << 1) ^ ((r & 7) << 4));
            *reinterpret_cast<short8*>(reinterpret_cast<char*>(&As[buf][0]) + byte) = avB[i];
            *reinterpret_cast<short8*>(reinterpret_cast<char*>(&Bs[buf][0]) + byte) = bvB[i];
        }
    };
    auto domfma = [&](int buf) {
        #pragma unroll
        for (int kt = 0; kt < 2; ++kt) {
            const int kbyte = (kt << 6) + ((lane >> 4) << 4);
            const int ar = (w << 4) + (lane & 15);
            short8 a = *reinterpret_cast<const short8*>(
                reinterpret_cast<char*>(&As[buf][0]) + (ar << 7) + (kbyte ^ ((ar & 7) << 4)));
            #pragma unroll
            for (int nt = 0; nt < 4; ++nt) {
                const int br = (nt << 4) + (lane & 15);
                short8 bb = *reinterpret_cast<const short8*>(
                    reinterpret_cast<char*>(&Bs[buf][0]) + (br << 7) + (kbyte ^ ((br & 7) << 4)));
                acc[nt] = __builtin_amdgcn_mfma_f32_16x16x32_bf16(a, bb, acc[nt], 0, 0, 0);
            }
        }
    };

    // prologue: buf0 <- k0; regA <- k1; regB <- k2
    loadA(0);
    wrA(0);
    if (nsteps > 1) loadA(64);
    if (nsteps > 2) loadB(128);
    __syncthreads();

    int cur = 0, s = 0;
    while (s + 1 < nsteps) {
        domfma(cur);
        wrA(cur ^ 1);
        if (s + 3 < nsteps) loadA((s + 3) << 6);
        __syncthreads(); cur ^= 1; ++s;
        if (s + 1 < nsteps) {
            domfma(cur);
            wrB(cur ^ 1);
            if (s + 3 < nsteps) loadB((s + 3) << 6);
            __syncthreads(); cur ^= 1; ++s;
        }
    }
    domfma(cur);

    #pragma unroll
    for (int nt = 0; nt < 4; ++nt) {
        const int col = n0 + (nt << 4) + (lane & 15);
        if (col < N) {
            const float bv = bias[col];
            #pragma unroll
            for (int r = 0; r < 4; ++r) {
                const int row = m0 + (w << 4) + ((lane >> 4) << 2) + r;
                float v = acc[nt][r] + bv;
                if (MODE == 1) v = fmaxf(v, 0.f);
                const long o = (long)row * N + col;
                if (MODE == 2) v = x0[o] * v + xin[o];
                if (WF32) outF[oz + o] = v;
                if (WB16) outB[oz + o] = f2b(v);
            }
        }
    }
}

// ---------------------------------------------------------------------------
// LayerNorm over 392 (block per row), f32 + bf16 outputs
// ---------------------------------------------------------------------------
__global__ __launch_bounds__(256) void ln_kernel(
    const float* __restrict__ in,
    const float* __restrict__ gamma, const float* __restrict__ beta,
    float* __restrict__ outF, short* __restrict__ outB)
{
    __shared__ float red[2][4];
    __shared__ float stats[2];
    const int b = blockIdx.x, t = threadIdx.x, lane = t & 63, w = t >> 6;
    const long base = (long)b * DD;
    float v0 = in[base + t];
    float v1 = (t < 136) ? in[base + 256 + t] : 0.f;
    float s = v0 + v1, q2 = v0 * v0 + v1 * v1;
    #pragma unroll
    for (int off = 32; off > 0; off >>= 1) {
        s += __shfl_xor(s, off);
        q2 += __shfl_xor(q2, off);
    }
    if (lane == 0) { red[0][w] = s; red[1][w] = q2; }
    __syncthreads();
    if (t == 0) {
        float S = red[0][0] + red[0][1] + red[0][2] + red[0][3];
        float Q = red[1][0] + red[1][1] + red[1][2] + red[1][3];
        float mean = S / (float)DD;
        float var = Q / (float)DD - mean * mean;
        stats[0] = mean;
        stats[1] = rsqrtf(var + 1e-5f);
    }
    __syncthreads();
    const float mean = stats[0], inv = stats[1];
    float o0 = (v0 - mean) * inv * gamma[t] + beta[t];
    outF[base + t] = o0; outB[base + t] = f2b(o0);
    if (t < 136) {
        float o1 = (v1 - mean) * inv * gamma[256 + t] + beta[256 + t];
        outF[base + 256 + t] = o1; outB[base + 256 + t] = f2b(o1);
    }
}

// ---------------------------------------------------------------------------
// K3: gates (from x f32) + expert-head dots (from h1 bf16 via hw2) + mix.
// ---------------------------------------------------------------------------
__global__ __launch_bounds__(256) void final_kernel(
    const float* __restrict__ x, const short* __restrict__ h1,
    const float* __restrict__ hw2, const float* __restrict__ hc,
    const float* __restrict__ gate_w, const float* __restrict__ gate_b,
    const float* __restrict__ head_b, float* __restrict__ out)
{
    const int t = threadIdx.x, lane = t & 63, w = t >> 6;
    const int b = blockIdx.x * 4 + w;
    const float* xr = x + (long)b * DD;

    float xv[7];
    #pragma unroll
    for (int i = 0; i < 7; ++i) {
        int d = lane + (i << 6);
        xv[i] = (d < DD) ? xr[d] : 0.f;
    }

    float gl[8] = {0.f, 0.f, 0.f, 0.f, 0.f, 0.f, 0.f, 0.f};
    #pragma unroll
    for (int i = 0; i < 7; ++i) {
        int d = lane + (i << 6);
        if (d < DD) {
            float4 g0 = *reinterpret_cast<const float4*>(&gate_w[d << 2]);
            float4 g1 = *reinterpret_cast<const float4*>(&gate_w[1568 + (d << 2)]);
            gl[0] = fmaf(xv[i], g0.x, gl[0]); gl[1] = fmaf(xv[i], g0.y, gl[1]);
            gl[2] = fmaf(xv[i], g0.z, gl[2]); gl[3] = fmaf(xv[i], g0.w, gl[3]);
            gl[4] = fmaf(xv[i], g1.x, gl[4]); gl[5] = fmaf(xv[i], g1.y, gl[5]);
            gl[6] = fmaf(xv[i], g1.z, gl[6]); gl[7] = fmaf(xv[i], g1.w, gl[7]);
        }
    }

    float ed[8];
    #pragma unroll
    for (int e = 0; e < 4; ++e) {
        short4v hv = *reinterpret_cast<const short4v*>(
            &h1[((long)e * BB + b) * HH1 + (lane << 2)]);
        const float* hwp = &hw2[(((e << 8) + (lane << 2))) << 1];
        float4 w01 = *reinterpret_cast<const float4*>(hwp);
        float4 w23 = *reinterpret_cast<const float4*>(hwp + 4);
        float h0 = b2f(hv[0]), h1f = b2f(hv[1]), h2 = b2f(hv[2]), h3 = b2f(hv[3]);
        ed[e]     = fmaf(h0, w01.x, fmaf(h1f, w01.z, fmaf(h2, w23.x, h3 * w23.z)));
        ed[4 + e] = fmaf(h0, w01.y, fmaf(h1f, w01.w, fmaf(h2, w23.y, h3 * w23.w)));
    }

    #pragma unroll
    for (int v = 0; v < 8; ++v) {
        #pragma unroll
        for (int off = 32; off > 0; off >>= 1) {
            gl[v] += __shfl_xor(gl[v], off);
            ed[v] += __shfl_xor(ed[v], off);
        }
    }

    if (lane == 0) {
        float res[2];
        #pragma unroll
        for (int tt = 0; tt < 2; ++tt) {
            float lv[4], m = -1e30f;
            #pragma unroll
            for (int e = 0; e < 4; ++e) {
                lv[e] = gl[tt * 4 + e] + gate_b[tt * 4 + e];
                m = fmaxf(m, lv[e]);
            }
            float sum = 0.f, acc = 0.f;
            #pragma unroll
            for (int e = 0; e < 4; ++e) { lv[e] = __expf(lv[e] - m); sum += lv[e]; }
            #pragma unroll
            for (int e = 0; e < 4; ++e)
                acc = fmaf(lv[e], ed[tt * 4 + e] + hc[e * 2 + tt], acc);
            res[tt] = head_b[tt] + acc / sum;
        }
        out[b] = res[0];
        out[BB + b] = res[1];
    }
}

// ---------------------------------------------------------------------------
extern "C" void kernel_launch(void* const* d_in, const int* in_sizes, int n_in,
                              void* d_out, int out_size, void* d_ws, size_t ws_size,
                              hipStream_t stream) {
    const int*   userId    = (const int*)d_in[0];
    const int*   movieId   = (const int*)d_in[1];
    const int*   seq       = (const int*)d_in[2];
    const float* dense     = (const float*)d_in[3];
    const float* emb_user  = (const float*)d_in[4];
    const float* emb_movie = (const float*)d_in[5];
    const float* att_w1    = (const float*)d_in[6];
    const float* att_b1    = (const float*)d_in[7];
    const float* att_w2    = (const float*)d_in[8];
    const float* att_b2    = (const float*)d_in[9];
    const float* in_gamma  = (const float*)d_in[10];
    const float* in_beta   = (const float*)d_in[11];
    const float* cr_gamma  = (const float*)d_in[12];
    const float* cr_beta   = (const float*)d_in[13];
    const float* cross_W   = (const float*)d_in[14];
    const float* cross_b   = (const float*)d_in[15];
    const float* exp_w1    = (const float*)d_in[16];
    const float* exp_b1    = (const float*)d_in[17];
    const float* exp_w2    = (const float*)d_in[18];
    const float* exp_b2    = (const float*)d_in[19];
    const float* gate_w    = (const float*)d_in[20];
    const float* gate_b    = (const float*)d_in[21];
    const float* head_w    = (const float*)d_in[22];
    const float* head_b    = (const float*)d_in[23];
    float* outp = (float*)d_out;

    char* p = (char*)d_ws;
    auto alloc = [&](size_t bytes) -> char* {
        char* r = p; p += (bytes + 255) & ~(size_t)255; return r;
    };
    short* WqpT  = (short*)alloc(8192 * 2);
    float* WkpFf = (float*)alloc(16384 * 4);
    float* hw2 = (float*)alloc(2048 * 4);
    float* hc  = (float*)alloc(8 * 4);
    short* WTc = (short*)alloc((size_t)3 * 392 * 392 * 2);
    short* WT1 = (short*)alloc((size_t)4 * 256 * 392 * 2);
    short* embB = (short*)alloc((size_t)50001 * 128 * 2);
    short* qb   = (short*)alloc((size_t)BB * DE * 2);
    float* qcAll = (float*)alloc((size_t)BB * 64 * 4);
    float* x0f = (float*)alloc((size_t)BB * DD * 4);
    short* x0b = (short*)alloc((size_t)BB * DD * 2);
    float* xAf = (float*)alloc((size_t)BB * DD * 4);
    short* xAb = (short*)alloc((size_t)BB * DD * 2);
    float* xBf = (float*)alloc((size_t)BB * DD * 4);
    short* xBb = (short*)alloc((size_t)BB * DD * 2);
    short* h1b = (short*)alloc((size_t)4 * BB * HH1 * 2);

    prep_small<<<68, 256, 0, stream>>>(att_w1, exp_w2, exp_b2, head_w,
                                       WqpT, WkpFf, hw2, hc);
    prep_trans<<<(S0 + S1 + S2 + S3 + 255) / 256, 256, 0, stream>>>(
        cross_W, exp_w1, emb_movie, movieId, WTc, WT1, embB, qb);

    // qcAll = qb @ WqpT^T + att_b1   [8192][64] f32; grid 128 (%8==0)
    bgemm<0, 1, 0, 1, 1><<<128, 256, 0, stream>>>(
        qb, WqpT, att_b1, qcAll, nullptr, nullptr, nullptr,
        BB, 64, DE, 0, 0, 0, 0);

    attn_kernel<<<BB, 256, 0, stream>>>(userId, movieId, seq, dense,
                                        emb_user, emb_movie, embB,
                                        qcAll, WkpFf,
                                        att_w2, att_b2,
                                        in_gamma, in_beta, x0f, x0b);

    // CrossNetV2: grid = 128 m-blocks * 7 n-blocks = 896 (%8==0)
    bgemm<2, 1, 1, 7, 1><<<896, 256, 0, stream>>>(x0b, WTc, cross_b, xAf, xAb,
                                                  x0f, x0f, BB, DD, DD, 0, 0, 0, 0);
    bgemm<2, 1, 1, 7, 1><<<896, 256, 0, stream>>>(xAb, WTc + 392 * 392, cross_b + 392,
                                                  xBf, xBb, x0f, xAf, BB, DD, DD, 0, 0, 0, 0);
    bgemm<2, 1, 0, 7, 1><<<896, 256, 0, stream>>>(xBb, WTc + 2 * 392 * 392, cross_b + 784,
                                                  xAf, nullptr, x0f, xBf, BB, DD, DD, 0, 0, 0, 0);

    // LN2: xAf -> xBf (+bf16)
    ln_kernel<<<BB, 256, 0, stream>>>(xAf, cr_gamma, cr_beta, xBf, xBb);

    // Experts layer 1: h1 = relu(x @ w1 + b1)  [E][B][256] bf16
    bgemm<1, 0, 1, 4, 4><<<2048, 256, 0, stream>>>(
        xBb, WT1, exp_b1, nullptr, h1b, nullptr, nullptr,
        BB, HH1, DD, 0, (long)HH1 * DD, HH1, (long)BB * HH1);

    // gates + expert-head dots + mix -> logits [2][B]
    final_kernel<<<BB / 4, 256, 0, stream>>>(xBf, h1b, hw2, hc,
                                             gate_w, gate_b, head_b, outp);

    (void)in_sizes; (void)n_in; (void)out_size; (void)ws_size;
}